// Round 1
// baseline (94.675 us; speedup 1.0000x reference)
//
#include <hip/hip_runtime.h>
#include <math.h>

// CompressedAttention: B=4,S=4096,H=2,KVH=1,D=2,MD=5
// scores_ij = al_{h,i}*P_j + be_{h,i}*Q_j (rank-2); v colinear -> scalar out weight.
// R7: FUSED single kernel. The entire per-batch key table (P,Q,Cv,Cv) is
// 4096*16B = 64KB -> fits in LDS whole. 1024-thread blocks (16 waves) each
// prep all 4096 keys (4/thread), one barrier, then the packed-fp32 main loop
// (v_pk_fma, heads in lanes .x/.y) reads static LDS: no workspace, no prep
// kernel + graph gap, no double-buffer staging, no per-tile barriers.
// Grid 512 -> 2 blocks/CU (2*64KB LDS, 32 waves/CU). VGPR target <=64.

#define BQ 4
#define SQ 4096
#define MDQ 5
#define EPSQ 1e-6f
#define SCALEQ 16.0f
#define L2E 1.4426950408889634f
#define ISQ2 0.70710678118654752f

typedef float v2f __attribute__((ext_vector_type(2)));

__device__ __forceinline__ float fast_exp2(float x) {
#if __has_builtin(__builtin_amdgcn_exp2f)
    return __builtin_amdgcn_exp2f(x);
#else
    return __expf(x * 0.6931471805599453f);
#endif
}

#define BLOCK 1024
#define WAVES 16            // waves per block
#define RPT 2               // rows per thread (per wave)
#define ROWSB (WAVES * RPT) // 32 rows per block
#define TILES (SQ / ROWSB)  // 128 tiles per batch -> grid 512 (2 blocks/CU)
#define KPT (SQ / BLOCK)    // 4 keys per thread in prep phase
#define JPT (SQ / 64)       // 64 inner iterations (keys per lane)

__global__ __launch_bounds__(BLOCK, 8)
void ca_fused(const float* __restrict__ x,
              const float* __restrict__ freqs,
              const float* __restrict__ qk_v,
              const float* __restrict__ v_v,
              const float* __restrict__ o_v,
              const float* __restrict__ vproj_u,
              const float* __restrict__ q_u,
              const float* __restrict__ k_u,
              const float* __restrict__ o_u,
              float* __restrict__ out)
{
    __shared__ float4 sKey[SQ];   // 64 KB: (P, Q, Cv, Cv) per key

    const int tid = threadIdx.x;
    const int sp  = tid & 63;        // key lane within wave
    const int w   = tid >> 6;        // wave index
    const int bx  = blockIdx.x;
    const int b   = bx / TILES;
    const int tile = bx % TILES;

    // ---- tiny shared params (broadcast / scalar loads) ----
    const float w0 = k_u[0], w1 = k_u[1];
    const float mk  = 0.5f * (w0 * w0 + w1 * w1);
    const float Mmu = SCALEQ * rsqrtf(mk);     // exact bound on |mu_j|

    const float qk0 = qk_v[0], qk1 = qk_v[1], qk2 = qk_v[2], qk3 = qk_v[3], qk4 = qk_v[4];
    const float vv0 = v_v[0],  vv1 = v_v[1],  vv2 = v_v[2],  vv3 = v_v[3],  vv4 = v_v[4];

    // ---- prep phase: 4 keys per thread into LDS ----
#pragma unroll
    for (int kk = 0; kk < KPT; ++kk) {
        const int j = tid + kk * BLOCK;
        const float* xr = x + (size_t)(b * SQ + j) * MDQ;
        const float x0 = xr[0], x1 = xr[1], x2 = xr[2], x3 = xr[3], x4 = xr[4];
        const float a  = x0*qk0 + x1*qk1 + x2*qk2 + x3*qk3 + x4*qk4;
        const float sv = x0*vv0 + x1*vv1 + x2*vv2 + x3*vv3 + x4*vv4;
        float sj, cj;
        __sincosf(freqs[j], &sj, &cj);
        const float mu = SCALEQ * a * rsqrtf(a * a * mk + EPSQ);   // rmsnorm(k) scalar
        sKey[j] = make_float4(mu * cj, mu * sj, sv, sv);           // Cv duplicated
    }

    // ---- per-row score coefficients, heads packed in v2f lanes ----
    const float u00 = q_u[0], u01 = q_u[1], u10 = q_u[2], u11 = q_u[3];
    const float m0 = 0.5f * (u00 * u00 + u01 * u01);
    const float m1 = 0.5f * (u10 * u10 + u11 * u11);
    const float A0 = u00 * w0 + u01 * w1, B0 = u01 * w0 - u00 * w1;
    const float A1 = u10 * w0 + u11 * w1, B1 = u11 * w0 - u10 * w1;

    const int i0 = tile * ROWSB + w * RPT;   // first row of this wave

    v2f al[RPT], be[RPT], Cc[RPT];
#pragma unroll
    for (int k = 0; k < RPT; ++k) {
        const int i = i0 + k;
        const float* xi = x + (size_t)(b * SQ + i) * MDQ;
        const float ai = xi[0]*qk0 + xi[1]*qk1 + xi[2]*qk2 + xi[3]*qk3 + xi[4]*qk4;
        float si, ci;
        __sincosf(freqs[i], &si, &ci);
        const float lam0 = SCALEQ * ai * rsqrtf(ai * ai * m0 + EPSQ);
        const float lam1 = SCALEQ * ai * rsqrtf(ai * ai * m1 + EPSQ);
        const float a0  = lam0 * (A0 * ci - B0 * si) * ISQ2;
        const float b0_ = lam0 * (A0 * si + B0 * ci) * ISQ2;
        const float a1  = lam1 * (A1 * ci - B1 * si) * ISQ2;
        const float b1_ = lam1 * (A1 * si + B1 * ci) * ISQ2;
        const float r0 = sqrtf(a0 * a0 + b0_ * b0_);
        const float r1 = sqrtf(a1 * a1 + b1_ * b1_);
        al[k] = (v2f){a0 * L2E, a1 * L2E};
        be[k] = (v2f){b0_ * L2E, b1_ * L2E};
        Cc[k] = (v2f){-r0 * Mmu * L2E, -r1 * Mmu * L2E};
    }

    __syncthreads();   // key table complete

    // ---- main loop: all keys from static LDS, no further barriers ----
    v2f l[RPT], n[RPT];
#pragma unroll
    for (int k = 0; k < RPT; ++k) { l[k] = (v2f){0.f, 0.f}; n[k] = (v2f){0.f, 0.f}; }

    const float4* __restrict__ kb = &sKey[sp];
#pragma unroll 8
    for (int jj = 0; jj < JPT; ++jj) {
        const float4 v = kb[jj * 64];
        const v2f vx = (v2f){v.x, v.x};
        const v2f vy = (v2f){v.y, v.y};
        const v2f vz = (v2f){v.z, v.w};      // Cv duplicated by prep
#pragma unroll
        for (int k = 0; k < RPT; ++k) {
            const v2f s = al[k] * vx + (be[k] * vy + Cc[k]);   // 2x v_pk_fma
            v2f e;
            e.x = fast_exp2(s.x);
            e.y = fast_exp2(s.y);
            l[k] += e;                        // v_pk_add
            n[k] += e * vz;                   // v_pk_fma
        }
    }

    // ---- full-wave butterfly reduction (64 key-lanes of this wave) ----
#pragma unroll
    for (int m = 1; m < 64; m <<= 1) {
#pragma unroll
        for (int k = 0; k < RPT; ++k) {
            l[k].x += __shfl_xor(l[k].x, m, 64);
            l[k].y += __shfl_xor(l[k].y, m, 64);
            n[k].x += __shfl_xor(n[k].x, m, 64);
            n[k].y += __shfl_xor(n[k].y, m, 64);
        }
    }

    // ---- epilogue: lanes 0..RPT-1 each write one row ----
    if (sp < RPT) {
        const int k = sp;
        const float L0 = fmaxf(l[k].x, 1e-30f);
        const float L1 = fmaxf(l[k].y, 1e-30f);
        const float W0 = n[k].x / L0, W1 = n[k].y / L1;

        const float p0 = vproj_u[0], p1 = vproj_u[1];
        const float d0 = p0 * o_v[0] + p1 * o_v[1];
        const float d1 = p0 * o_v[2] + p1 * o_v[3];
        const float so = W0 * d0 + W1 * d1;

        float* orow = out + (size_t)(b * SQ + i0 + k) * MDQ;
        orow[0] = so * o_u[0];
        orow[1] = so * o_u[1];
        orow[2] = so * o_u[2];
        orow[3] = so * o_u[3];
        orow[4] = so * o_u[4];
    }
}

extern "C" void kernel_launch(void* const* d_in, const int* in_sizes, int n_in,
                              void* d_out, int out_size, void* d_ws, size_t ws_size,
                              hipStream_t stream) {
    (void)in_sizes; (void)n_in; (void)out_size; (void)d_ws; (void)ws_size;
    const float* x       = (const float*)d_in[0];
    const float* freqs   = (const float*)d_in[1];
    const float* qk_v    = (const float*)d_in[2];
    const float* v_v     = (const float*)d_in[3];
    const float* o_v     = (const float*)d_in[4];
    const float* vproj_u = (const float*)d_in[5];
    const float* q_u     = (const float*)d_in[6];
    const float* k_u     = (const float*)d_in[7];
    const float* o_u     = (const float*)d_in[8];
    float* out = (float*)d_out;

    hipLaunchKernelGGL(ca_fused, dim3(BQ * TILES), dim3(BLOCK), 0, stream,
                       x, freqs, qk_v, v_v, o_v, vproj_u, q_u, k_u, o_u, out);
}

// Round 2
// 92.581 us; speedup vs baseline: 1.0226x; 1.0226x over previous
//
#include <hip/hip_runtime.h>
#include <math.h>

// CompressedAttention: B=4,S=4096,H=2,KVH=1,D=2,MD=5
// scores_ij = al_{h,i}*P_j + be_{h,i}*Q_j (rank-2); v colinear -> scalar out weight.
// R8: fused kernel, RPT 2->4. Pipe model: exp trans-floor 6.8us (134M exps,
// irreducible); LDS was 10.2us at RPT=2 (each wave re-reads the 64KB key
// table for only 2 rows). RPT=4 halves LDS reads/row -> 5.1us, under the
// trans floor. BLOCK=512 (8 waves) keeps grid=512 -> 2 blocks/CU (128KB LDS),
// 4 waves/SIMD; unroll-8 independent exps keep trans pipe fed. VGPR ~60 < 128.

#define BQ 4
#define SQ 4096
#define MDQ 5
#define EPSQ 1e-6f
#define SCALEQ 16.0f
#define L2E 1.4426950408889634f
#define ISQ2 0.70710678118654752f

typedef float v2f __attribute__((ext_vector_type(2)));

__device__ __forceinline__ float fast_exp2(float x) {
#if __has_builtin(__builtin_amdgcn_exp2f)
    return __builtin_amdgcn_exp2f(x);
#else
    return __expf(x * 0.6931471805599453f);
#endif
}

#define BLOCK 512
#define WAVES 8             // waves per block
#define RPT 4               // rows per thread (per wave)
#define ROWSB (WAVES * RPT) // 32 rows per block
#define TILES (SQ / ROWSB)  // 128 tiles per batch -> grid 512 (2 blocks/CU)
#define KPT (SQ / BLOCK)    // 8 keys per thread in prep phase
#define JPT (SQ / 64)       // 64 inner iterations (keys per lane)

__global__ __launch_bounds__(BLOCK, 4)
void ca_fused(const float* __restrict__ x,
              const float* __restrict__ freqs,
              const float* __restrict__ qk_v,
              const float* __restrict__ v_v,
              const float* __restrict__ o_v,
              const float* __restrict__ vproj_u,
              const float* __restrict__ q_u,
              const float* __restrict__ k_u,
              const float* __restrict__ o_u,
              float* __restrict__ out)
{
    __shared__ float4 sKey[SQ];   // 64 KB: (P, Q, Cv, Cv) per key

    const int tid = threadIdx.x;
    const int sp  = tid & 63;        // key lane within wave
    const int w   = tid >> 6;        // wave index
    const int bx  = blockIdx.x;
    const int b   = bx / TILES;
    const int tile = bx % TILES;

    // ---- tiny shared params (broadcast / scalar loads) ----
    const float w0 = k_u[0], w1 = k_u[1];
    const float mk  = 0.5f * (w0 * w0 + w1 * w1);
    const float Mmu = SCALEQ * rsqrtf(mk);     // exact bound on |mu_j|

    const float qk0 = qk_v[0], qk1 = qk_v[1], qk2 = qk_v[2], qk3 = qk_v[3], qk4 = qk_v[4];
    const float vv0 = v_v[0],  vv1 = v_v[1],  vv2 = v_v[2],  vv3 = v_v[3],  vv4 = v_v[4];

    // ---- prep phase: 8 keys per thread into LDS ----
#pragma unroll
    for (int kk = 0; kk < KPT; ++kk) {
        const int j = tid + kk * BLOCK;
        const float* xr = x + (size_t)(b * SQ + j) * MDQ;
        const float x0 = xr[0], x1 = xr[1], x2 = xr[2], x3 = xr[3], x4 = xr[4];
        const float a  = x0*qk0 + x1*qk1 + x2*qk2 + x3*qk3 + x4*qk4;
        const float sv = x0*vv0 + x1*vv1 + x2*vv2 + x3*vv3 + x4*vv4;
        float sj, cj;
        __sincosf(freqs[j], &sj, &cj);
        const float mu = SCALEQ * a * rsqrtf(a * a * mk + EPSQ);   // rmsnorm(k) scalar
        sKey[j] = make_float4(mu * cj, mu * sj, sv, sv);           // Cv duplicated
    }

    // ---- per-row score coefficients, heads packed in v2f lanes ----
    const float u00 = q_u[0], u01 = q_u[1], u10 = q_u[2], u11 = q_u[3];
    const float m0 = 0.5f * (u00 * u00 + u01 * u01);
    const float m1 = 0.5f * (u10 * u10 + u11 * u11);
    const float A0 = u00 * w0 + u01 * w1, B0 = u01 * w0 - u00 * w1;
    const float A1 = u10 * w0 + u11 * w1, B1 = u11 * w0 - u10 * w1;

    const int i0 = tile * ROWSB + w * RPT;   // first row of this wave

    v2f al[RPT], be[RPT], Cc[RPT];
#pragma unroll
    for (int k = 0; k < RPT; ++k) {
        const int i = i0 + k;
        const float* xi = x + (size_t)(b * SQ + i) * MDQ;
        const float ai = xi[0]*qk0 + xi[1]*qk1 + xi[2]*qk2 + xi[3]*qk3 + xi[4]*qk4;
        float si, ci;
        __sincosf(freqs[i], &si, &ci);
        const float lam0 = SCALEQ * ai * rsqrtf(ai * ai * m0 + EPSQ);
        const float lam1 = SCALEQ * ai * rsqrtf(ai * ai * m1 + EPSQ);
        const float a0  = lam0 * (A0 * ci - B0 * si) * ISQ2;
        const float b0_ = lam0 * (A0 * si + B0 * ci) * ISQ2;
        const float a1  = lam1 * (A1 * ci - B1 * si) * ISQ2;
        const float b1_ = lam1 * (A1 * si + B1 * ci) * ISQ2;
        const float r0 = sqrtf(a0 * a0 + b0_ * b0_);
        const float r1 = sqrtf(a1 * a1 + b1_ * b1_);
        al[k] = (v2f){a0 * L2E, a1 * L2E};
        be[k] = (v2f){b0_ * L2E, b1_ * L2E};
        Cc[k] = (v2f){-r0 * Mmu * L2E, -r1 * Mmu * L2E};
    }

    __syncthreads();   // key table complete

    // ---- main loop: all keys from static LDS, no further barriers ----
    v2f l[RPT], n[RPT];
#pragma unroll
    for (int k = 0; k < RPT; ++k) { l[k] = (v2f){0.f, 0.f}; n[k] = (v2f){0.f, 0.f}; }

    const float4* __restrict__ kb = &sKey[sp];
#pragma unroll 8
    for (int jj = 0; jj < JPT; ++jj) {
        const float4 v = kb[jj * 64];
        const v2f vx = (v2f){v.x, v.x};
        const v2f vy = (v2f){v.y, v.y};
        const v2f vz = (v2f){v.z, v.w};      // Cv duplicated by prep
#pragma unroll
        for (int k = 0; k < RPT; ++k) {
            const v2f s = al[k] * vx + (be[k] * vy + Cc[k]);   // 2x v_pk_fma
            v2f e;
            e.x = fast_exp2(s.x);
            e.y = fast_exp2(s.y);
            l[k] += e;                        // v_pk_add
            n[k] += e * vz;                   // v_pk_fma
        }
    }

    // ---- full-wave butterfly reduction (64 key-lanes of this wave) ----
#pragma unroll
    for (int m = 1; m < 64; m <<= 1) {
#pragma unroll
        for (int k = 0; k < RPT; ++k) {
            l[k].x += __shfl_xor(l[k].x, m, 64);
            l[k].y += __shfl_xor(l[k].y, m, 64);
            n[k].x += __shfl_xor(n[k].x, m, 64);
            n[k].y += __shfl_xor(n[k].y, m, 64);
        }
    }

    // ---- epilogue: lanes 0..RPT-1 each write one row ----
    if (sp < RPT) {
        const int k = sp;
        const float L0 = fmaxf(l[k].x, 1e-30f);
        const float L1 = fmaxf(l[k].y, 1e-30f);
        const float W0 = n[k].x / L0, W1 = n[k].y / L1;

        const float p0 = vproj_u[0], p1 = vproj_u[1];
        const float d0 = p0 * o_v[0] + p1 * o_v[1];
        const float d1 = p0 * o_v[2] + p1 * o_v[3];
        const float so = W0 * d0 + W1 * d1;

        float* orow = out + (size_t)(b * SQ + i0 + k) * MDQ;
        orow[0] = so * o_u[0];
        orow[1] = so * o_u[1];
        orow[2] = so * o_u[2];
        orow[3] = so * o_u[3];
        orow[4] = so * o_u[4];
    }
}

extern "C" void kernel_launch(void* const* d_in, const int* in_sizes, int n_in,
                              void* d_out, int out_size, void* d_ws, size_t ws_size,
                              hipStream_t stream) {
    (void)in_sizes; (void)n_in; (void)out_size; (void)d_ws; (void)ws_size;
    const float* x       = (const float*)d_in[0];
    const float* freqs   = (const float*)d_in[1];
    const float* qk_v    = (const float*)d_in[2];
    const float* v_v     = (const float*)d_in[3];
    const float* o_v     = (const float*)d_in[4];
    const float* vproj_u = (const float*)d_in[5];
    const float* q_u     = (const float*)d_in[6];
    const float* k_u     = (const float*)d_in[7];
    const float* o_u     = (const float*)d_in[8];
    float* out = (float*)d_out;

    hipLaunchKernelGGL(ca_fused, dim3(BQ * TILES), dim3(BLOCK), 0, stream,
                       x, freqs, qk_v, v_v, o_v, vproj_u, q_u, k_u, o_u, out);
}